// Round 14
// baseline (445.301 us; speedup 1.0000x reference)
//
#include <hip/hip_runtime.h>
#include <math.h>

#define NNODES 50000
#define NEDGES 400000
#define ETOT   (NEDGES + NNODES)
#define NGRAPHS 64
#define NCVT   (NNODES*32)

typedef _Float16 f16;
typedef _Float16 f16x4 __attribute__((ext_vector_type(4)));
typedef _Float16 f16x8 __attribute__((ext_vector_type(8)));
typedef float f32x4 __attribute__((ext_vector_type(4)));

__device__ __forceinline__ float lrelu(float x){ return x >= 0.f ? x : 0.2f*x; }
__device__ __forceinline__ float eluf(float x){ return x > 0.f ? x : expm1f(x); }

// ---------------- CSR build (self-loop at slot 0; deg counts edges only, +1 in scans) ----------------
__global__ void k_hist(const int* __restrict__ ei, int* __restrict__ deg){
  int e = blockIdx.x*blockDim.x + threadIdx.x;
  if (e < NEDGES) atomicAdd(&deg[ei[NEDGES + e]], 1);
}
__global__ void k_scan1(const int* __restrict__ deg, int* __restrict__ part, int n){
  __shared__ int buf[256];
  int i = blockIdx.x*256 + threadIdx.x;
  buf[threadIdx.x] = (i<n)? deg[i]+1 : 0;
  __syncthreads();
  for (int s=128; s>0; s>>=1){ if (threadIdx.x < s) buf[threadIdx.x]+=buf[threadIdx.x+s]; __syncthreads(); }
  if (threadIdx.x==0) part[blockIdx.x]=buf[0];
}
__global__ void k_scan2(const int* __restrict__ part, int* __restrict__ bpre, int* __restrict__ row_off_last, int nb){
  __shared__ int buf[256];
  int t = threadIdx.x;
  int v = (t<nb)? part[t] : 0;
  buf[t]=v; __syncthreads();
  for (int s=1;s<256;s<<=1){ int a = (t>=s)? buf[t-s]:0; __syncthreads(); buf[t]+=a; __syncthreads(); }
  if (t<nb) bpre[t] = buf[t]-v;
  if (t==255) row_off_last[0] = buf[255];
}
__global__ void k_scan3(const int* __restrict__ deg, const int* __restrict__ bpre, int* __restrict__ row_off, int n){
  __shared__ int buf[256];
  int t = threadIdx.x;
  int i = blockIdx.x*256 + t;
  int v = (i<n)? deg[i]+1 : 0;
  buf[t]=v; __syncthreads();
  for (int s=1;s<256;s<<=1){ int a=(t>=s)?buf[t-s]:0; __syncthreads(); buf[t]+=a; __syncthreads(); }
  if (i<n) row_off[i] = bpre[blockIdx.x] + buf[t]-v;
}
__global__ void k_selfpos(const int* __restrict__ row_off, int* __restrict__ csr_src,
                          int* __restrict__ csr_dst, int* __restrict__ cursor){
  int n = blockIdx.x*256 + threadIdx.x;
  if (n < NNODES){
    int p = row_off[n];
    csr_src[p] = n; csr_dst[p] = n;
    cursor[n] = 1;
  }
}
__global__ void k_scatter(const int* __restrict__ ei, const int* __restrict__ row_off,
                          int* __restrict__ cursor, int* __restrict__ csr_src, int* __restrict__ csr_dst){
  int e = blockIdx.x*blockDim.x + threadIdx.x;
  if (e < NEDGES){
    int s = ei[e], d = ei[NEDGES+e];
    int pos = row_off[d] + atomicAdd(&cursor[d],1);
    csr_src[pos] = s; csr_dst[pos] = d;
  }
}

// ---------------- weight prep + x cast (merged) ----------------
__global__ void k_prep(const float* __restrict__ x, f16* __restrict__ xh,
                       const float* __restrict__ W1, const float* __restrict__ W2, const float* __restrict__ W3,
                       const float* __restrict__ as1, const float* __restrict__ ad1,
                       const float* __restrict__ as2, const float* __restrict__ ad2,
                       const float* __restrict__ as3, const float* __restrict__ ad3,
                       f16* __restrict__ BT1, f16* __restrict__ BT2, f16* __restrict__ BT3,
                       f16* __restrict__ PT1x, f16* __restrict__ PT2, f16* __restrict__ PT3){
  int u = blockIdx.x*256 + threadIdx.x;
  if (u < NCVT){
    float4 v = *(const float4*)&x[(size_t)u*4];
    f16x4 o; o[0]=(f16)v.x; o[1]=(f16)v.y; o[2]=(f16)v.z; o[3]=(f16)v.w;
    *(f16x4*)&xh[(size_t)u*4] = o;
    return;
  }
  u -= NCVT;
  if (u < 8192){ int j=u>>7, k=u&127; BT1[j*128+k] = (f16)W1[(size_t)k*64+j]; return; }
  u -= 8192;
  if (u < 16384){ int col=u>>6, k=u&63; BT2[col*64+k] = (f16)W2[(size_t)k*256+col]; return; }
  u -= 16384;
  if (u < 131072){ int j=u>>10, t=u&1023, h=t>>8, c=t&255;
                   BT3[(size_t)j*1024+t] = (f16)W3[(size_t)c*512 + h*128 + j]; return; }
  u -= 131072;
  if (u < 2048){ // PT1x[o][k] = sum_c W1[k][h*16+c] * a1_h[c]
    int o=u>>7, k=u&127; float v=0.f;
    if (o<8){ int h=o&3;
      const float* a=((o<4)?as1:ad1)+h*16; const float* w=W1+(size_t)k*64+h*16;
      for(int c=0;c<16;c++) v=fmaf(w[c],a[c],v); }
    PT1x[u] = (f16)v; return; }
  u -= 2048;
  if (u < 1024){ // PT2[o][k]
    int o=u>>6, k=u&63; float v=0.f;
    if (o<8){ int h=o&3;
      const float* a=((o<4)?as2:ad2)+h*64; const float* w=W2+(size_t)k*256+h*64;
      for(int c=0;c<64;c++) v=fmaf(w[c],a[c],v); }
    PT2[u] = (f16)v; return; }
  u -= 1024;
  if (u < 4096){ // PT3[o][k]
    int o=u>>8, k=u&255; float v=0.f;
    if (o<8){ int h=o&3;
      const float* a=((o<4)?as3:ad3)+h*128; const float* w=W3+(size_t)k*512+h*128;
      for(int c=0;c<128;c++) v=fmaf(w[c],a[c],v); }
    PT3[u] = (f16)v; }
}

// ---------------- scores via MFMA: esd[n][0..3]=es, [4..7]=ed ----------------
template<int KF>
__global__ __launch_bounds__(256) void k_scores_m(const f16* __restrict__ g, const f16* __restrict__ PT,
                                                  float* __restrict__ esd){
  int wv = threadIdx.x>>6, lane = threadIdx.x&63;
  int r = lane&15, kb = lane>>4;
  int row0 = blockIdx.x*64 + wv*16;
  const f16* arow = g + (size_t)(row0+r)*KF + kb*8;
  const f16* brow = PT + (size_t)r*KF + kb*8;
  f32x4 acc = {0,0,0,0};
  #pragma unroll
  for (int k0=0;k0<KF;k0+=32){
    f16x8 af = *(const f16x8*)(arow + k0);
    f16x8 bf = *(const f16x8*)(brow + k0);
    acc = __builtin_amdgcn_mfma_f32_16x16x32_f16(af, bf, acc, 0,0,0);
  }
  if (r < 8){
    #pragma unroll
    for (int i=0;i<4;i++){
      int row = row0 + kb*4 + i;
      if (row < NNODES) esd[(size_t)row*8 + r] = acc[i];
    }
  }
}

// ---------------- edge-parallel softmax numerators: alphaW[p][h] ----------------
__global__ __launch_bounds__(256) void k_expw(const float* __restrict__ esd, const int* __restrict__ csr_src,
                                              const int* __restrict__ csr_dst, float* __restrict__ alphaW){
  int p = blockIdx.x*256 + threadIdx.x;
  if (p >= ETOT) return;
  int s = csr_src[p], d = csr_dst[p];
  float4 a = *(const float4*)&esd[(size_t)s*8];
  float4 b = *(const float4*)&esd[(size_t)d*8+4];
  float4 r;
  r.x = expf(lrelu(a.x+b.x));
  r.y = expf(lrelu(a.y+b.y));
  r.z = expf(lrelu(a.z+b.z));
  r.w = expf(lrelu(a.w+b.w));
  *(float4*)&alphaW[(size_t)p*4] = r;
}

// ---------------- MFMA GEMMs ----------------
// l1: h1[50000,64] = xh @ BT1^T, fused layer-1 scores esd = xh @ PT1x
__global__ __launch_bounds__(256) void k_mfma_l1(const f16* __restrict__ xh, const f16* __restrict__ BT1,
                                                 const f16* __restrict__ PT1x,
                                                 f16* __restrict__ h1h, float* __restrict__ esd){
  int wv = threadIdx.x>>6, lane = threadIdx.x&63;
  int r = lane&15, kb = lane>>4;
  int row0 = blockIdx.x*64 + wv*16;
  const f16* arow = xh + (size_t)(row0 + r)*128 + kb*8;
  f32x4 acc[4] = {{0,0,0,0},{0,0,0,0},{0,0,0,0},{0,0,0,0}};
  f32x4 accs = {0,0,0,0};
  for (int k0=0;k0<128;k0+=32){
    f16x8 af = *(const f16x8*)(arow + k0);
    #pragma unroll
    for (int c=0;c<4;c++){
      f16x8 bf = *(const f16x8*)(BT1 + (size_t)(c*16+r)*128 + k0 + kb*8);
      acc[c] = __builtin_amdgcn_mfma_f32_16x16x32_f16(af, bf, acc[c], 0,0,0);
    }
    f16x8 bs = *(const f16x8*)(PT1x + (size_t)r*128 + k0 + kb*8);
    accs = __builtin_amdgcn_mfma_f32_16x16x32_f16(af, bs, accs, 0,0,0);
  }
  #pragma unroll
  for (int c=0;c<4;c++)
    #pragma unroll
    for (int i=0;i<4;i++){
      int row = row0 + kb*4 + i;
      if (row < NNODES) h1h[(size_t)row*64 + c*16 + r] = (f16)acc[c][i];
    }
  if (r < 8){
    #pragma unroll
    for (int i=0;i<4;i++){
      int row = row0 + kb*4 + i;
      if (row < NNODES) esd[(size_t)row*8 + r] = accs[i];
    }
  }
}

// l2 (per-head): g2[n, h*64+j] = ELU(agg2[n, h*64+:] @ W2_h + b2)
__global__ __launch_bounds__(256) void k_mfma_l2(const f16* __restrict__ agg2h, const f16* __restrict__ BT2,
                                                 const float* __restrict__ b2, f16* __restrict__ g2h){
  int wv = threadIdx.x>>6, lane = threadIdx.x&63;
  int r = lane&15, kb = lane>>4;
  int h = blockIdx.y;
  int row0 = blockIdx.x*64 + wv*16;
  const f16* arow = agg2h + (size_t)(row0 + r)*256 + h*64 + kb*8;
  f32x4 acc[4] = {{0,0,0,0},{0,0,0,0},{0,0,0,0},{0,0,0,0}};
  #pragma unroll
  for (int k0=0;k0<64;k0+=32){
    f16x8 af = *(const f16x8*)(arow + k0);
    #pragma unroll
    for (int c=0;c<4;c++){
      f16x8 bf = *(const f16x8*)(BT2 + (size_t)(h*64+c*16+r)*64 + k0 + kb*8);
      acc[c] = __builtin_amdgcn_mfma_f32_16x16x32_f16(af, bf, acc[c], 0,0,0);
    }
  }
  #pragma unroll
  for (int c=0;c<4;c++){
    int col = h*64 + c*16 + r;
    float bb = b2[col];
    #pragma unroll
    for (int i=0;i<4;i++){
      int row = row0 + kb*4 + i;
      if (row < NNODES) g2h[(size_t)row*256 + col] = (f16)eluf(acc[c][i] + bb);
    }
  }
}

// ---------------- gathers (1 node/wave — scheduler backfill balances degrees) ----------------
__global__ __launch_bounds__(256) void k_gat1f(const f16* __restrict__ h1h, const float* __restrict__ alphaW,
    const int* __restrict__ row_off, const int* __restrict__ csr_src,
    const float* __restrict__ b1, f16* __restrict__ g1h){
  int n = blockIdx.x*4 + (threadIdx.x>>6);
  if (n >= NNODES) return;
  int t = threadIdx.x & 63;
  int head = t >> 4;
  int pos = row_off[n], end = row_off[n+1];
  float acc = 0.f, den = 0.f;
  for (; pos+3 < end; pos += 4){
    int s0 = csr_src[pos], s1 = csr_src[pos+1], s2 = csr_src[pos+2], s3 = csr_src[pos+3];
    float w0 = alphaW[(size_t)pos*4 + head];
    float w1 = alphaW[(size_t)(pos+1)*4 + head];
    float w2 = alphaW[(size_t)(pos+2)*4 + head];
    float w3 = alphaW[(size_t)(pos+3)*4 + head];
    float v0 = (float)h1h[(size_t)s0*64 + t];
    float v1 = (float)h1h[(size_t)s1*64 + t];
    float v2 = (float)h1h[(size_t)s2*64 + t];
    float v3 = (float)h1h[(size_t)s3*64 + t];
    acc = fmaf(w0, v0, fmaf(w1, v1, fmaf(w2, v2, fmaf(w3, v3, acc))));
    den += (w0 + w1) + (w2 + w3);
  }
  for (; pos < end; ++pos){
    int s0 = csr_src[pos];
    float w0 = alphaW[(size_t)pos*4 + head];
    acc = fmaf(w0, (float)h1h[(size_t)s0*64 + t], acc);
    den += w0;
  }
  g1h[(size_t)n*64 + t] = (f16)eluf(acc/(den + 1e-16f) + b1[t]);
}

__global__ __launch_bounds__(256) void k_agg2f(const f16* __restrict__ g1h, const float* __restrict__ alphaW,
    const int* __restrict__ row_off, const int* __restrict__ csr_src,
    f16* __restrict__ agg2h){
  int n = blockIdx.x*4 + (threadIdx.x>>6);
  if (n >= NNODES) return;
  int t = threadIdx.x & 63;
  int pos = row_off[n], end = row_off[n+1];
  float c0=0.f,c1=0.f,c2=0.f,c3=0.f,d0=0.f,d1=0.f,d2=0.f,d3=0.f;
  for (; pos+3 < end; pos += 4){
    int s0 = csr_src[pos], s1 = csr_src[pos+1], s2 = csr_src[pos+2], s3 = csr_src[pos+3];
    float4 a = *(const float4*)&alphaW[(size_t)pos*4];
    float4 b = *(const float4*)&alphaW[(size_t)(pos+1)*4];
    float4 c = *(const float4*)&alphaW[(size_t)(pos+2)*4];
    float4 d = *(const float4*)&alphaW[(size_t)(pos+3)*4];
    float v0 = (float)g1h[(size_t)s0*64 + t];
    float v1 = (float)g1h[(size_t)s1*64 + t];
    float v2 = (float)g1h[(size_t)s2*64 + t];
    float v3 = (float)g1h[(size_t)s3*64 + t];
    c0=fmaf(a.x,v0,fmaf(b.x,v1,fmaf(c.x,v2,fmaf(d.x,v3,c0))));
    c1=fmaf(a.y,v0,fmaf(b.y,v1,fmaf(c.y,v2,fmaf(d.y,v3,c1))));
    c2=fmaf(a.z,v0,fmaf(b.z,v1,fmaf(c.z,v2,fmaf(d.z,v3,c2))));
    c3=fmaf(a.w,v0,fmaf(b.w,v1,fmaf(c.w,v2,fmaf(d.w,v3,c3))));
    d0+=(a.x+b.x)+(c.x+d.x); d1+=(a.y+b.y)+(c.y+d.y);
    d2+=(a.z+b.z)+(c.z+d.z); d3+=(a.w+b.w)+(c.w+d.w);
  }
  for (; pos < end; ++pos){
    int s0 = csr_src[pos];
    float4 a = *(const float4*)&alphaW[(size_t)pos*4];
    float v0 = (float)g1h[(size_t)s0*64 + t];
    c0=fmaf(a.x,v0,c0); c1=fmaf(a.y,v0,c1); c2=fmaf(a.z,v0,c2); c3=fmaf(a.w,v0,c3);
    d0+=a.x; d1+=a.y; d2+=a.z; d3+=a.w;
  }
  size_t base = (size_t)n*256;
  agg2h[base       + t] = (f16)(c0/(d0+1e-16f));
  agg2h[base +  64 + t] = (f16)(c1/(d1+1e-16f));
  agg2h[base + 128 + t] = (f16)(c2/(d2+1e-16f));
  agg2h[base + 192 + t] = (f16)(c3/(d3+1e-16f));
}

// ---------------- fused layer3: gather(g2h) -> LDS -> GEMM(BT3) -> g3 ----------------
// block = 64 nodes, 1024 threads (16 waves). Gather: dynamic node-claim (LDS ctr).
// GEMM: A from LDS (pad row 1032 f16), B from L2-resident BT3; epilogue mean/bias/ELU.
__global__ __launch_bounds__(1024) void k_agg3z(const f16* __restrict__ g2h, const float* __restrict__ alphaW,
    const int* __restrict__ row_off, const int* __restrict__ csr_src,
    const f16* __restrict__ BT3, const float* __restrict__ b3, float* __restrict__ g3){
  __shared__ __align__(16) f16 Az[64][1032];
  __shared__ int ctr;
  int tid = threadIdx.x;
  int wv = tid>>6, lane = tid&63;
  if (tid==0) ctr = 0;
  __syncthreads();
  int nbase = blockIdx.x*64;
  for (;;){
    int i = 0;
    if (lane==0) i = atomicAdd(&ctr, 1);
    i = __shfl(i, 0, 64);
    if (i >= 64) break;
    int n = nbase + i;
    if (n >= NNODES) continue;
    int pos = row_off[n], end = row_off[n+1];
    float acc[4][4] = {};
    float d0=0.f,d1=0.f,d2=0.f,d3=0.f;
    for (; pos+3 < end; pos += 4){
      int s0 = csr_src[pos], s1 = csr_src[pos+1], s2 = csr_src[pos+2], s3 = csr_src[pos+3];
      float4 a = *(const float4*)&alphaW[(size_t)pos*4];
      float4 b = *(const float4*)&alphaW[(size_t)(pos+1)*4];
      float4 c = *(const float4*)&alphaW[(size_t)(pos+2)*4];
      float4 d = *(const float4*)&alphaW[(size_t)(pos+3)*4];
      f16x4 u0 = *(const f16x4*)&g2h[(size_t)s0*256 + lane*4];
      f16x4 u1 = *(const f16x4*)&g2h[(size_t)s1*256 + lane*4];
      f16x4 u2 = *(const f16x4*)&g2h[(size_t)s2*256 + lane*4];
      f16x4 u3 = *(const f16x4*)&g2h[(size_t)s3*256 + lane*4];
      float wa[4] = {a.x,a.y,a.z,a.w};
      float wb[4] = {b.x,b.y,b.z,b.w};
      float wc[4] = {c.x,c.y,c.z,c.w};
      float wd[4] = {d.x,d.y,d.z,d.w};
      #pragma unroll
      for (int h=0;h<4;h++)
        #pragma unroll
        for (int j=0;j<4;j++)
          acc[h][j] = fmaf(wa[h],(float)u0[j], fmaf(wb[h],(float)u1[j],
                      fmaf(wc[h],(float)u2[j], fmaf(wd[h],(float)u3[j], acc[h][j]))));
      d0 += (a.x+b.x)+(c.x+d.x); d1 += (a.y+b.y)+(c.y+d.y);
      d2 += (a.z+b.z)+(c.z+d.z); d3 += (a.w+b.w)+(c.w+d.w);
    }
    for (; pos < end; ++pos){
      int s0 = csr_src[pos];
      float4 a = *(const float4*)&alphaW[(size_t)pos*4];
      f16x4 u0 = *(const f16x4*)&g2h[(size_t)s0*256 + lane*4];
      float wa[4] = {a.x,a.y,a.z,a.w};
      #pragma unroll
      for (int h=0;h<4;h++)
        #pragma unroll
        for (int j=0;j<4;j++)
          acc[h][j] = fmaf(wa[h], (float)u0[j], acc[h][j]);
      d0 += a.x; d1 += a.y; d2 += a.z; d3 += a.w;
    }
    float dn[4] = {d0+1e-16f, d1+1e-16f, d2+1e-16f, d3+1e-16f};
    #pragma unroll
    for (int h=0;h<4;h++){
      f16x4 o;
      #pragma unroll
      for (int j=0;j<4;j++) o[j] = (f16)(acc[h][j]/dn[h]);
      *(f16x4*)&Az[i][h*256 + lane*4] = o;
    }
  }
  __syncthreads();
  // GEMM phase: wave wv -> rows (wv&3)*16.., cols (wv>>2)*32..
  int r = lane&15, kb = lane>>4;
  int rq = wv & 3, cq = wv >> 2;
  const f16* bp0 = BT3 + (size_t)(cq*32 + r)*1024 + kb*8;
  const f16* bp1 = bp0 + (size_t)16*1024;
  f32x4 acc0 = {0,0,0,0}, acc1 = {0,0,0,0};
  for (int k0=0;k0<1024;k0+=32){
    f16x8 af = *(const f16x8*)&Az[rq*16 + r][k0 + kb*8];
    acc0 = __builtin_amdgcn_mfma_f32_16x16x32_f16(af, *(const f16x8*)(bp0+k0), acc0, 0,0,0);
    acc1 = __builtin_amdgcn_mfma_f32_16x16x32_f16(af, *(const f16x8*)(bp1+k0), acc1, 0,0,0);
  }
  int col0 = cq*32 + r;
  int col1 = col0 + 16;
  float bb0 = b3[col0], bb1 = b3[col1];
  #pragma unroll
  for (int i=0;i<4;i++){
    int row = nbase + rq*16 + kb*4 + i;
    if (row < NNODES){
      g3[(size_t)row*128 + col0] = eluf(0.25f*acc0[i] + bb0);
      g3[(size_t)row*128 + col1] = eluf(0.25f*acc1[i] + bb1);
    }
  }
}

// ---------------- pooling + linear head ----------------
__device__ __forceinline__ int lowerb(const int* a, int n, int v){
  int lo=0, hi=n;
  while (lo<hi){ int mid=(lo+hi)>>1; if (a[mid]<v) lo=mid+1; else hi=mid; }
  return lo;
}
__global__ void k_pool8(const float* __restrict__ g3, const int* __restrict__ batch, float* __restrict__ pooledS){
  int g = blockIdx.x, ch = blockIdx.y, c = threadIdx.x;
  int lo = lowerb(batch, NNODES, g);
  int hi = lowerb(batch, NNODES, g+1);
  int len = hi - lo;
  int b0 = lo + (len*ch)/8, b1 = lo + (len*(ch+1))/8;
  float s = 0.f;
  for (int nn=b0; nn<b1; ++nn) s += g3[(size_t)nn*128 + c];
  if (b1 > b0) atomicAdd(&pooledS[g*128+c], s);
}
__global__ void k_lin(const float* __restrict__ pooledS, const int* __restrict__ batch,
                      const float* __restrict__ Wlin, const float* __restrict__ blin, float* __restrict__ out){
  int t = threadIdx.x;
  if (t < 640){
    int g = t/10, j = t%10;
    int lo = lowerb(batch, NNODES, g);
    int hi = lowerb(batch, NNODES, g+1);
    float inv = 1.f / fmaxf((float)(hi-lo), 1.f);
    float s = blin[j];
    for (int c=0;c<128;c++) s = fmaf(pooledS[g*128+c]*inv, Wlin[c*10+j], s);
    out[t] = s;
  }
}

extern "C" void kernel_launch(void* const* d_in, const int* in_sizes, int n_in,
                              void* d_out, int out_size, void* d_ws, size_t ws_size,
                              hipStream_t stream){
  (void)in_sizes; (void)n_in; (void)out_size; (void)ws_size;
  const float* x    = (const float*)d_in[0];
  const int*   ei   = (const int*)d_in[1];
  const int*   batch= (const int*)d_in[2];
  const float* W1   = (const float*)d_in[3];
  const float* as1  = (const float*)d_in[4];
  const float* ad1  = (const float*)d_in[5];
  const float* b1   = (const float*)d_in[6];
  const float* W2   = (const float*)d_in[7];
  const float* as2  = (const float*)d_in[8];
  const float* ad2  = (const float*)d_in[9];
  const float* b2   = (const float*)d_in[10];
  const float* W3   = (const float*)d_in[11];
  const float* as3  = (const float*)d_in[12];
  const float* ad3  = (const float*)d_in[13];
  const float* b3   = (const float*)d_in[14];
  const float* Wlin = (const float*)d_in[15];
  const float* blin = (const float*)d_in[16];
  float* out = (float*)d_out;

  char* ws = (char*)d_ws;
  size_t off = 0;
  auto alloc = [&](size_t bytes)->char*{ char* p = ws + off; off += (bytes + 255) & ~(size_t)255; return p; };
  int* csr_src = (int*)alloc((size_t)ETOT*4);
  int* csr_dst = (int*)alloc((size_t)ETOT*4);
  int* row_off = (int*)alloc((size_t)(NNODES+1)*4);
  int* deg     = (int*)alloc((size_t)NNODES*4);
  int* cursor  = (int*)alloc((size_t)NNODES*4);
  int* part    = (int*)alloc(256*4);
  int* bpre    = (int*)alloc(256*4);
  float* esd   = (float*)alloc((size_t)NNODES*8*4);
  float* alphaW= (float*)alloc((size_t)ETOT*4*4);
  f16* BT1     = (f16*)alloc(8192*2);
  f16* BT2     = (f16*)alloc(16384*2);
  f16* BT3     = (f16*)alloc(131072*2);
  f16* PT1x    = (f16*)alloc(2048*2);
  f16* PT2     = (f16*)alloc(1024*2);
  f16* PT3     = (f16*)alloc(4096*2);
  float* pooledS = (float*)alloc((size_t)NGRAPHS*128*4);
  f16* g2h     = (f16*)alloc((size_t)NNODES*256*2);   // 25.6 MB (live through layer 3)
  f16* xh      = (f16*)alloc((size_t)NNODES*128*2);   // 12.8 MB
  f16* h1h     = (f16*)alloc((size_t)NNODES*64*2);    //  6.4 MB
  f16* g1h     = (f16*)alloc((size_t)NNODES*64*2);    //  6.4 MB
  f16* agg2h   = (f16*)alloc((size_t)NNODES*256*2);   // 25.6 MB
  float* g3    = (float*)alloc((size_t)NNODES*128*4); // 25.6 MB (absorbs OOB-read tails)
  alloc(4096);                                        // tail guard for vector reads

  int nbE = (NEDGES+255)/256;
  int nbS = (NNODES+255)/256;
  int nbP = (ETOT+255)/256;
  int nb4 = (NNODES+3)/4;

  // CSR with self-loop at slot 0 of each row (deg holds edge count; +1 in scans)
  hipMemsetAsync(deg, 0, (size_t)NNODES*4, stream);
  k_hist<<<nbE,256,0,stream>>>(ei, deg);
  k_scan1<<<nbS,256,0,stream>>>(deg, part, NNODES);
  k_scan2<<<1,256,0,stream>>>(part, bpre, row_off+NNODES, nbS);
  k_scan3<<<nbS,256,0,stream>>>(deg, bpre, row_off, NNODES);
  k_selfpos<<<nbS,256,0,stream>>>(row_off, csr_src, csr_dst, cursor);
  k_scatter<<<nbE,256,0,stream>>>(ei, row_off, cursor, csr_src, csr_dst);

  // weight prep + x cast (merged)
  k_prep<<<6886,256,0,stream>>>(x, xh, W1,W2,W3,as1,ad1,as2,ad2,as3,ad3,BT1,BT2,BT3,PT1x,PT2,PT3);

  // layer 1 (scores fused into the GEMM)
  k_mfma_l1<<<782,256,0,stream>>>(xh, BT1, PT1x, h1h, esd);
  k_expw<<<nbP,256,0,stream>>>(esd, csr_src, csr_dst, alphaW);
  k_gat1f<<<nb4,256,0,stream>>>(h1h, alphaW, row_off, csr_src, b1, g1h);

  // layer 2
  k_scores_m<64><<<782,256,0,stream>>>(g1h, PT2, esd);
  k_expw<<<nbP,256,0,stream>>>(esd, csr_src, csr_dst, alphaW);
  k_agg2f<<<nb4,256,0,stream>>>(g1h, alphaW, row_off, csr_src, agg2h);
  k_mfma_l2<<<dim3(782,4),256,0,stream>>>(agg2h, BT2, b2, g2h);

  // layer 3: scores -> expw -> fused gather+GEMM
  k_scores_m<256><<<782,256,0,stream>>>(g2h, PT3, esd);
  k_expw<<<nbP,256,0,stream>>>(esd, csr_src, csr_dst, alphaW);
  k_agg3z<<<782,1024,0,stream>>>(g2h, alphaW, row_off, csr_src, BT3, b3, g3);

  // pool + linear
  hipMemsetAsync(pooledS, 0, (size_t)NGRAPHS*128*4, stream);
  k_pool8<<<dim3(NGRAPHS,8),128,0,stream>>>(g3, batch, pooledS);
  k_lin<<<1,1024,0,stream>>>(pooledS, batch, Wlin, blin, out);
}

// Round 15
// 364.713 us; speedup vs baseline: 1.2210x; 1.2210x over previous
//
#include <hip/hip_runtime.h>
#include <math.h>

#define NNODES 50000
#define NEDGES 400000
#define ETOT   (NEDGES + NNODES)
#define NGRAPHS 64
#define NCVT   (NNODES*32)

typedef _Float16 f16;
typedef _Float16 f16x4 __attribute__((ext_vector_type(4)));
typedef _Float16 f16x8 __attribute__((ext_vector_type(8)));
typedef float f32x4 __attribute__((ext_vector_type(4)));

__device__ __forceinline__ float lrelu(float x){ return x >= 0.f ? x : 0.2f*x; }
__device__ __forceinline__ float eluf(float x){ return x > 0.f ? x : expm1f(x); }

// ---------------- CSR build (self-loop at slot 0; deg counts edges only, +1 in scans) ----------------
__global__ void k_hist(const int* __restrict__ ei, int* __restrict__ deg){
  int e = blockIdx.x*blockDim.x + threadIdx.x;
  if (e < NEDGES) atomicAdd(&deg[ei[NEDGES + e]], 1);
}
__global__ void k_scan1(const int* __restrict__ deg, int* __restrict__ part, int n){
  __shared__ int buf[256];
  int i = blockIdx.x*256 + threadIdx.x;
  buf[threadIdx.x] = (i<n)? deg[i]+1 : 0;
  __syncthreads();
  for (int s=128; s>0; s>>=1){ if (threadIdx.x < s) buf[threadIdx.x]+=buf[threadIdx.x+s]; __syncthreads(); }
  if (threadIdx.x==0) part[blockIdx.x]=buf[0];
}
__global__ void k_scan2(const int* __restrict__ part, int* __restrict__ bpre, int* __restrict__ row_off_last, int nb){
  __shared__ int buf[256];
  int t = threadIdx.x;
  int v = (t<nb)? part[t] : 0;
  buf[t]=v; __syncthreads();
  for (int s=1;s<256;s<<=1){ int a = (t>=s)? buf[t-s]:0; __syncthreads(); buf[t]+=a; __syncthreads(); }
  if (t<nb) bpre[t] = buf[t]-v;
  if (t==255) row_off_last[0] = buf[255];
}
__global__ void k_scan3(const int* __restrict__ deg, const int* __restrict__ bpre, int* __restrict__ row_off, int n){
  __shared__ int buf[256];
  int t = threadIdx.x;
  int i = blockIdx.x*256 + t;
  int v = (i<n)? deg[i]+1 : 0;
  buf[t]=v; __syncthreads();
  for (int s=1;s<256;s<<=1){ int a=(t>=s)?buf[t-s]:0; __syncthreads(); buf[t]+=a; __syncthreads(); }
  if (i<n) row_off[i] = bpre[blockIdx.x] + buf[t]-v;
}
__global__ void k_selfpos(const int* __restrict__ row_off, int* __restrict__ csr_src,
                          int* __restrict__ csr_dst, int* __restrict__ cursor){
  int n = blockIdx.x*256 + threadIdx.x;
  if (n < NNODES){
    int p = row_off[n];
    csr_src[p] = n; csr_dst[p] = n;
    cursor[n] = 1;
  }
}
__global__ void k_scatter(const int* __restrict__ ei, const int* __restrict__ row_off,
                          int* __restrict__ cursor, int* __restrict__ csr_src, int* __restrict__ csr_dst){
  int e = blockIdx.x*blockDim.x + threadIdx.x;
  if (e < NEDGES){
    int s = ei[e], d = ei[NEDGES+e];
    int pos = row_off[d] + atomicAdd(&cursor[d],1);
    csr_src[pos] = s; csr_dst[pos] = d;
  }
}

// ---------------- weight prep + x cast (merged) ----------------
__global__ void k_prep(const float* __restrict__ x, f16* __restrict__ xh,
                       const float* __restrict__ W1, const float* __restrict__ W2, const float* __restrict__ W3,
                       const float* __restrict__ as1, const float* __restrict__ ad1,
                       const float* __restrict__ as2, const float* __restrict__ ad2,
                       const float* __restrict__ as3, const float* __restrict__ ad3,
                       f16* __restrict__ BT1, f16* __restrict__ BT2, f16* __restrict__ BT3,
                       f16* __restrict__ PT1x, f16* __restrict__ PT2, f16* __restrict__ PT3){
  int u = blockIdx.x*256 + threadIdx.x;
  if (u < NCVT){
    float4 v = *(const float4*)&x[(size_t)u*4];
    f16x4 o; o[0]=(f16)v.x; o[1]=(f16)v.y; o[2]=(f16)v.z; o[3]=(f16)v.w;
    *(f16x4*)&xh[(size_t)u*4] = o;
    return;
  }
  u -= NCVT;
  if (u < 8192){ int j=u>>7, k=u&127; BT1[j*128+k] = (f16)W1[(size_t)k*64+j]; return; }
  u -= 8192;
  if (u < 16384){ int col=u>>6, k=u&63; BT2[col*64+k] = (f16)W2[(size_t)k*256+col]; return; }
  u -= 16384;
  if (u < 131072){ int j=u>>10, t=u&1023, h=t>>8, c=t&255;
                   BT3[(size_t)j*1024+t] = (f16)W3[(size_t)c*512 + h*128 + j]; return; }
  u -= 131072;
  if (u < 2048){ // PT1x[o][k] = sum_c W1[k][h*16+c] * a1_h[c]
    int o=u>>7, k=u&127; float v=0.f;
    if (o<8){ int h=o&3;
      const float* a=((o<4)?as1:ad1)+h*16; const float* w=W1+(size_t)k*64+h*16;
      for(int c=0;c<16;c++) v=fmaf(w[c],a[c],v); }
    PT1x[u] = (f16)v; return; }
  u -= 2048;
  if (u < 1024){ // PT2[o][k]
    int o=u>>6, k=u&63; float v=0.f;
    if (o<8){ int h=o&3;
      const float* a=((o<4)?as2:ad2)+h*64; const float* w=W2+(size_t)k*256+h*64;
      for(int c=0;c<64;c++) v=fmaf(w[c],a[c],v); }
    PT2[u] = (f16)v; return; }
  u -= 1024;
  if (u < 4096){ // PT3[o][k]
    int o=u>>8, k=u&255; float v=0.f;
    if (o<8){ int h=o&3;
      const float* a=((o<4)?as3:ad3)+h*128; const float* w=W3+(size_t)k*512+h*128;
      for(int c=0;c<128;c++) v=fmaf(w[c],a[c],v); }
    PT3[u] = (f16)v; }
}

// ---------------- scores via MFMA: esd[n][0..3]=es, [4..7]=ed ----------------
template<int KF>
__global__ __launch_bounds__(256) void k_scores_m(const f16* __restrict__ g, const f16* __restrict__ PT,
                                                  float* __restrict__ esd){
  int wv = threadIdx.x>>6, lane = threadIdx.x&63;
  int r = lane&15, kb = lane>>4;
  int row0 = blockIdx.x*64 + wv*16;
  const f16* arow = g + (size_t)(row0+r)*KF + kb*8;
  const f16* brow = PT + (size_t)r*KF + kb*8;
  f32x4 acc = {0,0,0,0};
  #pragma unroll
  for (int k0=0;k0<KF;k0+=32){
    f16x8 af = *(const f16x8*)(arow + k0);
    f16x8 bf = *(const f16x8*)(brow + k0);
    acc = __builtin_amdgcn_mfma_f32_16x16x32_f16(af, bf, acc, 0,0,0);
  }
  if (r < 8){
    #pragma unroll
    for (int i=0;i<4;i++){
      int row = row0 + kb*4 + i;
      if (row < NNODES) esd[(size_t)row*8 + r] = acc[i];
    }
  }
}

// ---------------- edge-parallel softmax numerators: alphaW[p][h] ----------------
__global__ __launch_bounds__(256) void k_expw(const float* __restrict__ esd, const int* __restrict__ csr_src,
                                              const int* __restrict__ csr_dst, float* __restrict__ alphaW){
  int p = blockIdx.x*256 + threadIdx.x;
  if (p >= ETOT) return;
  int s = csr_src[p], d = csr_dst[p];
  float4 a = *(const float4*)&esd[(size_t)s*8];
  float4 b = *(const float4*)&esd[(size_t)d*8+4];
  float4 r;
  r.x = expf(lrelu(a.x+b.x));
  r.y = expf(lrelu(a.y+b.y));
  r.z = expf(lrelu(a.z+b.z));
  r.w = expf(lrelu(a.w+b.w));
  *(float4*)&alphaW[(size_t)p*4] = r;
}

// ---------------- MFMA GEMMs ----------------
// l1: h1[50000,64] = xh @ BT1^T, fused layer-1 scores esd = xh @ PT1x
__global__ __launch_bounds__(256) void k_mfma_l1(const f16* __restrict__ xh, const f16* __restrict__ BT1,
                                                 const f16* __restrict__ PT1x,
                                                 f16* __restrict__ h1h, float* __restrict__ esd){
  int wv = threadIdx.x>>6, lane = threadIdx.x&63;
  int r = lane&15, kb = lane>>4;
  int row0 = blockIdx.x*64 + wv*16;
  const f16* arow = xh + (size_t)(row0 + r)*128 + kb*8;
  f32x4 acc[4] = {{0,0,0,0},{0,0,0,0},{0,0,0,0},{0,0,0,0}};
  f32x4 accs = {0,0,0,0};
  for (int k0=0;k0<128;k0+=32){
    f16x8 af = *(const f16x8*)(arow + k0);
    #pragma unroll
    for (int c=0;c<4;c++){
      f16x8 bf = *(const f16x8*)(BT1 + (size_t)(c*16+r)*128 + k0 + kb*8);
      acc[c] = __builtin_amdgcn_mfma_f32_16x16x32_f16(af, bf, acc[c], 0,0,0);
    }
    f16x8 bs = *(const f16x8*)(PT1x + (size_t)r*128 + k0 + kb*8);
    accs = __builtin_amdgcn_mfma_f32_16x16x32_f16(af, bs, accs, 0,0,0);
  }
  #pragma unroll
  for (int c=0;c<4;c++)
    #pragma unroll
    for (int i=0;i<4;i++){
      int row = row0 + kb*4 + i;
      if (row < NNODES) h1h[(size_t)row*64 + c*16 + r] = (f16)acc[c][i];
    }
  if (r < 8){
    #pragma unroll
    for (int i=0;i<4;i++){
      int row = row0 + kb*4 + i;
      if (row < NNODES) esd[(size_t)row*8 + r] = accs[i];
    }
  }
}

// l2 (per-head): g2[n, h*64+j] = ELU(agg2[n, h*64+:] @ W2_h + b2)
__global__ __launch_bounds__(256) void k_mfma_l2(const f16* __restrict__ agg2h, const f16* __restrict__ BT2,
                                                 const float* __restrict__ b2, f16* __restrict__ g2h){
  int wv = threadIdx.x>>6, lane = threadIdx.x&63;
  int r = lane&15, kb = lane>>4;
  int h = blockIdx.y;
  int row0 = blockIdx.x*64 + wv*16;
  const f16* arow = agg2h + (size_t)(row0 + r)*256 + h*64 + kb*8;
  f32x4 acc[4] = {{0,0,0,0},{0,0,0,0},{0,0,0,0},{0,0,0,0}};
  #pragma unroll
  for (int k0=0;k0<64;k0+=32){
    f16x8 af = *(const f16x8*)(arow + k0);
    #pragma unroll
    for (int c=0;c<4;c++){
      f16x8 bf = *(const f16x8*)(BT2 + (size_t)(h*64+c*16+r)*64 + k0 + kb*8);
      acc[c] = __builtin_amdgcn_mfma_f32_16x16x32_f16(af, bf, acc[c], 0,0,0);
    }
  }
  #pragma unroll
  for (int c=0;c<4;c++){
    int col = h*64 + c*16 + r;
    float bb = b2[col];
    #pragma unroll
    for (int i=0;i<4;i++){
      int row = row0 + kb*4 + i;
      if (row < NNODES) g2h[(size_t)row*256 + col] = (f16)eluf(acc[c][i] + bb);
    }
  }
}

// layer3 final GEMM, LDS-tiled + register prefetch:
// g3[n,128] = ELU(0.25 * aggz[n,1024] @ BT3^T + b3)
__global__ __launch_bounds__(256) void k_mfma_z(const f16* __restrict__ aggz, const f16* __restrict__ BT3,
                                                const float* __restrict__ b3, float* __restrict__ g3){
  __shared__ __align__(16) f16 As[64][72];
  __shared__ __align__(16) f16 Bs[128][72];
  int tid = threadIdx.x;
  int wv = tid>>6, lane = tid&63;
  int r = lane&15, kb = lane>>4;
  int rowbase = blockIdx.x*64;
  int ar = tid>>2, ap = (tid&3)*16;
  int bc = tid>>1, bp = (tid&1)*32;
  const f16* asrc = aggz + (size_t)(rowbase + ar)*1024 + ap;
  const f16* bsrc = BT3 + (size_t)bc*1024 + bp;
  f32x4 acc[8];
  #pragma unroll
  for (int c=0;c<8;c++) acc[c] = (f32x4){0,0,0,0};
  f16x8 ra0, ra1, rb0, rb1, rb2, rb3;
  ra0 = *(const f16x8*)(asrc);      ra1 = *(const f16x8*)(asrc+8);
  rb0 = *(const f16x8*)(bsrc);      rb1 = *(const f16x8*)(bsrc+8);
  rb2 = *(const f16x8*)(bsrc+16);   rb3 = *(const f16x8*)(bsrc+24);
  for (int kc=0; kc<16; ++kc){
    __syncthreads();
    *(f16x8*)&As[ar][ap]    = ra0;  *(f16x8*)&As[ar][ap+8]  = ra1;
    *(f16x8*)&Bs[bc][bp]    = rb0;  *(f16x8*)&Bs[bc][bp+8]  = rb1;
    *(f16x8*)&Bs[bc][bp+16] = rb2;  *(f16x8*)&Bs[bc][bp+24] = rb3;
    __syncthreads();
    if (kc+1 < 16){
      const f16* an = asrc + (kc+1)*64;
      const f16* bn = bsrc + (kc+1)*64;
      ra0 = *(const f16x8*)(an);    ra1 = *(const f16x8*)(an+8);
      rb0 = *(const f16x8*)(bn);    rb1 = *(const f16x8*)(bn+8);
      rb2 = *(const f16x8*)(bn+16); rb3 = *(const f16x8*)(bn+24);
    }
    #pragma unroll
    for (int ks=0;ks<2;ks++){
      f16x8 af = *(const f16x8*)&As[wv*16 + r][ks*32 + kb*8];
      #pragma unroll
      for (int c=0;c<8;c++){
        f16x8 bf = *(const f16x8*)&Bs[c*16 + r][ks*32 + kb*8];
        acc[c] = __builtin_amdgcn_mfma_f32_16x16x32_f16(af, bf, acc[c], 0,0,0);
      }
    }
  }
  #pragma unroll
  for (int c=0;c<8;c++){
    int col = c*16 + r;
    float bb = b3[col];
    #pragma unroll
    for (int i=0;i<4;i++){
      int row = rowbase + wv*16 + kb*4 + i;
      if (row < NNODES) g3[(size_t)row*128 + col] = eluf(0.25f*acc[c][i] + bb);
    }
  }
}

// ---------------- gathers (1 node/wave — scheduler backfill balances degrees) ----------------
__global__ __launch_bounds__(256) void k_gat1f(const f16* __restrict__ h1h, const float* __restrict__ alphaW,
    const int* __restrict__ row_off, const int* __restrict__ csr_src,
    const float* __restrict__ b1, f16* __restrict__ g1h){
  int n = blockIdx.x*4 + (threadIdx.x>>6);
  if (n >= NNODES) return;
  int t = threadIdx.x & 63;
  int head = t >> 4;
  int pos = row_off[n], end = row_off[n+1];
  float acc = 0.f, den = 0.f;
  for (; pos+3 < end; pos += 4){
    int s0 = csr_src[pos], s1 = csr_src[pos+1], s2 = csr_src[pos+2], s3 = csr_src[pos+3];
    float w0 = alphaW[(size_t)pos*4 + head];
    float w1 = alphaW[(size_t)(pos+1)*4 + head];
    float w2 = alphaW[(size_t)(pos+2)*4 + head];
    float w3 = alphaW[(size_t)(pos+3)*4 + head];
    float v0 = (float)h1h[(size_t)s0*64 + t];
    float v1 = (float)h1h[(size_t)s1*64 + t];
    float v2 = (float)h1h[(size_t)s2*64 + t];
    float v3 = (float)h1h[(size_t)s3*64 + t];
    acc = fmaf(w0, v0, fmaf(w1, v1, fmaf(w2, v2, fmaf(w3, v3, acc))));
    den += (w0 + w1) + (w2 + w3);
  }
  for (; pos < end; ++pos){
    int s0 = csr_src[pos];
    float w0 = alphaW[(size_t)pos*4 + head];
    acc = fmaf(w0, (float)h1h[(size_t)s0*64 + t], acc);
    den += w0;
  }
  g1h[(size_t)n*64 + t] = (f16)eluf(acc/(den + 1e-16f) + b1[t]);
}

__global__ __launch_bounds__(256) void k_agg2f(const f16* __restrict__ g1h, const float* __restrict__ alphaW,
    const int* __restrict__ row_off, const int* __restrict__ csr_src,
    f16* __restrict__ agg2h){
  int n = blockIdx.x*4 + (threadIdx.x>>6);
  if (n >= NNODES) return;
  int t = threadIdx.x & 63;
  int pos = row_off[n], end = row_off[n+1];
  float c0=0.f,c1=0.f,c2=0.f,c3=0.f,d0=0.f,d1=0.f,d2=0.f,d3=0.f;
  for (; pos+3 < end; pos += 4){
    int s0 = csr_src[pos], s1 = csr_src[pos+1], s2 = csr_src[pos+2], s3 = csr_src[pos+3];
    float4 a = *(const float4*)&alphaW[(size_t)pos*4];
    float4 b = *(const float4*)&alphaW[(size_t)(pos+1)*4];
    float4 c = *(const float4*)&alphaW[(size_t)(pos+2)*4];
    float4 d = *(const float4*)&alphaW[(size_t)(pos+3)*4];
    float v0 = (float)g1h[(size_t)s0*64 + t];
    float v1 = (float)g1h[(size_t)s1*64 + t];
    float v2 = (float)g1h[(size_t)s2*64 + t];
    float v3 = (float)g1h[(size_t)s3*64 + t];
    c0=fmaf(a.x,v0,fmaf(b.x,v1,fmaf(c.x,v2,fmaf(d.x,v3,c0))));
    c1=fmaf(a.y,v0,fmaf(b.y,v1,fmaf(c.y,v2,fmaf(d.y,v3,c1))));
    c2=fmaf(a.z,v0,fmaf(b.z,v1,fmaf(c.z,v2,fmaf(d.z,v3,c2))));
    c3=fmaf(a.w,v0,fmaf(b.w,v1,fmaf(c.w,v2,fmaf(d.w,v3,c3))));
    d0+=(a.x+b.x)+(c.x+d.x); d1+=(a.y+b.y)+(c.y+d.y);
    d2+=(a.z+b.z)+(c.z+d.z); d3+=(a.w+b.w)+(c.w+d.w);
  }
  for (; pos < end; ++pos){
    int s0 = csr_src[pos];
    float4 a = *(const float4*)&alphaW[(size_t)pos*4];
    float v0 = (float)g1h[(size_t)s0*64 + t];
    c0=fmaf(a.x,v0,c0); c1=fmaf(a.y,v0,c1); c2=fmaf(a.z,v0,c2); c3=fmaf(a.w,v0,c3);
    d0+=a.x; d1+=a.y; d2+=a.z; d3+=a.w;
  }
  size_t base = (size_t)n*256;
  agg2h[base       + t] = (f16)(c0/(d0+1e-16f));
  agg2h[base +  64 + t] = (f16)(c1/(d1+1e-16f));
  agg2h[base + 128 + t] = (f16)(c2/(d2+1e-16f));
  agg2h[base + 192 + t] = (f16)(c3/(d3+1e-16f));
}

// layer3 pre-GEMM aggregation: half-wave edge split, 16B loads.
// lanes 0-31 handle even edges, 32-63 odd edges; each lane owns 8 channels.
__global__ __launch_bounds__(256) void k_agg3n(const f16* __restrict__ g2h, const float* __restrict__ alphaW,
    const int* __restrict__ row_off, const int* __restrict__ csr_src,
    f16* __restrict__ aggz){
  int n = blockIdx.x*4 + (threadIdx.x>>6);
  if (n >= NNODES) return;
  int lane = threadIdx.x & 63;
  int half = lane >> 5;
  int c8 = (lane & 31)*8;
  int pos = row_off[n], end = row_off[n+1];
  float acc[4][8] = {};
  float dn0=0.f,dn1=0.f,dn2=0.f,dn3=0.f;
  for (; pos+3 < end; pos += 4){
    int sA = csr_src[pos + half];
    int sB = csr_src[pos + 2 + half];
    float4 wA = *(const float4*)&alphaW[(size_t)(pos+half)*4];
    float4 wB = *(const float4*)&alphaW[(size_t)(pos+2+half)*4];
    f16x8 uA = *(const f16x8*)&g2h[(size_t)sA*256 + c8];
    f16x8 uB = *(const f16x8*)&g2h[(size_t)sB*256 + c8];
    float wa[4] = {wA.x,wA.y,wA.z,wA.w};
    float wb[4] = {wB.x,wB.y,wB.z,wB.w};
    #pragma unroll
    for (int h=0;h<4;h++)
      #pragma unroll
      for (int j=0;j<8;j++)
        acc[h][j] = fmaf(wa[h], (float)uA[j], fmaf(wb[h], (float)uB[j], acc[h][j]));
    dn0 += wA.x+wB.x; dn1 += wA.y+wB.y; dn2 += wA.z+wB.z; dn3 += wA.w+wB.w;
  }
  for (; pos < end; ++pos){   // tail <=3 edges: half-0 lanes only
    int s = csr_src[pos];
    float4 w4 = *(const float4*)&alphaW[(size_t)pos*4];
    f16x8 u = *(const f16x8*)&g2h[(size_t)s*256 + c8];
    if (half == 0){
      float w[4] = {w4.x,w4.y,w4.z,w4.w};
      #pragma unroll
      for (int h=0;h<4;h++)
        #pragma unroll
        for (int j=0;j<8;j++)
          acc[h][j] = fmaf(w[h], (float)u[j], acc[h][j]);
      dn0+=w4.x; dn1+=w4.y; dn2+=w4.z; dn3+=w4.w;
    }
  }
  #pragma unroll
  for (int h=0;h<4;h++)
    #pragma unroll
    for (int j=0;j<8;j++)
      acc[h][j] += __shfl_xor(acc[h][j], 32, 64);
  dn0 += __shfl_xor(dn0,32,64); dn1 += __shfl_xor(dn1,32,64);
  dn2 += __shfl_xor(dn2,32,64); dn3 += __shfl_xor(dn3,32,64);
  float dnv[4] = {dn0+1e-16f, dn1+1e-16f, dn2+1e-16f, dn3+1e-16f};
  if (half == 0){
    #pragma unroll
    for (int h=0;h<4;h++){
      f16x8 o;
      #pragma unroll
      for (int j=0;j<8;j++) o[j] = (f16)(acc[h][j]/dnv[h]);
      *(f16x8*)&aggz[(size_t)n*1024 + h*256 + c8] = o;
    }
  }
}

// ---------------- pooling + linear head ----------------
__device__ __forceinline__ int lowerb(const int* a, int n, int v){
  int lo=0, hi=n;
  while (lo<hi){ int mid=(lo+hi)>>1; if (a[mid]<v) lo=mid+1; else hi=mid; }
  return lo;
}
__global__ void k_pool8(const float* __restrict__ g3, const int* __restrict__ batch, float* __restrict__ pooledS){
  int g = blockIdx.x, ch = blockIdx.y, c = threadIdx.x;
  int lo = lowerb(batch, NNODES, g);
  int hi = lowerb(batch, NNODES, g+1);
  int len = hi - lo;
  int b0 = lo + (len*ch)/8, b1 = lo + (len*(ch+1))/8;
  float s = 0.f;
  for (int nn=b0; nn<b1; ++nn) s += g3[(size_t)nn*128 + c];
  if (b1 > b0) atomicAdd(&pooledS[g*128+c], s);
}
__global__ void k_lin(const float* __restrict__ pooledS, const int* __restrict__ batch,
                      const float* __restrict__ Wlin, const float* __restrict__ blin, float* __restrict__ out){
  int t = threadIdx.x;
  if (t < 640){
    int g = t/10, j = t%10;
    int lo = lowerb(batch, NNODES, g);
    int hi = lowerb(batch, NNODES, g+1);
    float inv = 1.f / fmaxf((float)(hi-lo), 1.f);
    float s = blin[j];
    for (int c=0;c<128;c++) s = fmaf(pooledS[g*128+c]*inv, Wlin[c*10+j], s);
    out[t] = s;
  }
}

extern "C" void kernel_launch(void* const* d_in, const int* in_sizes, int n_in,
                              void* d_out, int out_size, void* d_ws, size_t ws_size,
                              hipStream_t stream){
  (void)in_sizes; (void)n_in; (void)out_size; (void)ws_size;
  const float* x    = (const float*)d_in[0];
  const int*   ei   = (const int*)d_in[1];
  const int*   batch= (const int*)d_in[2];
  const float* W1   = (const float*)d_in[3];
  const float* as1  = (const float*)d_in[4];
  const float* ad1  = (const float*)d_in[5];
  const float* b1   = (const float*)d_in[6];
  const float* W2   = (const float*)d_in[7];
  const float* as2  = (const float*)d_in[8];
  const float* ad2  = (const float*)d_in[9];
  const float* b2   = (const float*)d_in[10];
  const float* W3   = (const float*)d_in[11];
  const float* as3  = (const float*)d_in[12];
  const float* ad3  = (const float*)d_in[13];
  const float* b3   = (const float*)d_in[14];
  const float* Wlin = (const float*)d_in[15];
  const float* blin = (const float*)d_in[16];
  float* out = (float*)d_out;

  char* ws = (char*)d_ws;
  size_t off = 0;
  auto alloc = [&](size_t bytes)->char*{ char* p = ws + off; off += (bytes + 255) & ~(size_t)255; return p; };
  int* csr_src = (int*)alloc((size_t)ETOT*4);
  int* csr_dst = (int*)alloc((size_t)ETOT*4);
  int* row_off = (int*)alloc((size_t)(NNODES+1)*4);
  int* deg     = (int*)alloc((size_t)NNODES*4);
  int* cursor  = (int*)alloc((size_t)NNODES*4);
  int* part    = (int*)alloc(256*4);
  int* bpre    = (int*)alloc(256*4);
  float* esd   = (float*)alloc((size_t)NNODES*8*4);
  float* alphaW= (float*)alloc((size_t)ETOT*4*4);
  f16* BT1     = (f16*)alloc(8192*2);
  f16* BT2     = (f16*)alloc(16384*2);
  f16* BT3     = (f16*)alloc(131072*2);
  f16* PT1x    = (f16*)alloc(2048*2);
  f16* PT2     = (f16*)alloc(1024*2);
  f16* PT3     = (f16*)alloc(4096*2);
  float* pooledS = (float*)alloc((size_t)NGRAPHS*128*4);
  // g2h FIRST so the following five regions are contiguous and alias-able as aggz.
  f16* g2h     = (f16*)alloc((size_t)NNODES*256*2);   // 25.6 MB (live through layer 3)
  f16* xh      = (f16*)alloc((size_t)NNODES*128*2);   // 12.8 MB (aggz part 1)
  f16* h1h     = (f16*)alloc((size_t)NNODES*64*2);    //  6.4 MB (aggz part 2)
  f16* g1h     = (f16*)alloc((size_t)NNODES*64*2);    //  6.4 MB (aggz part 3)
  f16* agg2h   = (f16*)alloc((size_t)NNODES*256*2);   // 25.6 MB (aggz part 4)
  alloc((size_t)NNODES*512*2);                        // 51.2 MB zslab (aggz part 5)
  float* g3    = (float*)alloc((size_t)NNODES*128*4); // 25.6 MB (absorbs OOB-read tails)
  f16* aggz    = xh;  // [NNODES][1024] f16 spanning xh..zslab (all dead by agg3n)

  int nbE = (NEDGES+255)/256;
  int nbS = (NNODES+255)/256;
  int nbP = (ETOT+255)/256;
  int nb4 = (NNODES+3)/4;

  // CSR with self-loop at slot 0 of each row (deg holds edge count; +1 in scans)
  hipMemsetAsync(deg, 0, (size_t)NNODES*4, stream);
  k_hist<<<nbE,256,0,stream>>>(ei, deg);
  k_scan1<<<nbS,256,0,stream>>>(deg, part, NNODES);
  k_scan2<<<1,256,0,stream>>>(part, bpre, row_off+NNODES, nbS);
  k_scan3<<<nbS,256,0,stream>>>(deg, bpre, row_off, NNODES);
  k_selfpos<<<nbS,256,0,stream>>>(row_off, csr_src, csr_dst, cursor);
  k_scatter<<<nbE,256,0,stream>>>(ei, row_off, cursor, csr_src, csr_dst);

  // weight prep + x cast (merged)
  k_prep<<<6886,256,0,stream>>>(x, xh, W1,W2,W3,as1,ad1,as2,ad2,as3,ad3,BT1,BT2,BT3,PT1x,PT2,PT3);

  // layer 1 (scores fused into the GEMM)
  k_mfma_l1<<<782,256,0,stream>>>(xh, BT1, PT1x, h1h, esd);
  k_expw<<<nbP,256,0,stream>>>(esd, csr_src, csr_dst, alphaW);
  k_gat1f<<<nb4,256,0,stream>>>(h1h, alphaW, row_off, csr_src, b1, g1h);

  // layer 2
  k_scores_m<64><<<782,256,0,stream>>>(g1h, PT2, esd);
  k_expw<<<nbP,256,0,stream>>>(esd, csr_src, csr_dst, alphaW);
  k_agg2f<<<nb4,256,0,stream>>>(g1h, alphaW, row_off, csr_src, agg2h);
  k_mfma_l2<<<dim3(782,4),256,0,stream>>>(agg2h, BT2, b2, g2h);

  // layer 3: scores -> expw -> narrow gather (half-wave, 16B loads) -> LDS-tiled K=1024 GEMM
  k_scores_m<256><<<782,256,0,stream>>>(g2h, PT3, esd);
  k_expw<<<nbP,256,0,stream>>>(esd, csr_src, csr_dst, alphaW);
  k_agg3n<<<nb4,256,0,stream>>>(g2h, alphaW, row_off, csr_src, aggz);
  k_mfma_z<<<782,256,0,stream>>>(aggz, BT3, b3, g3);

  // pool + linear
  hipMemsetAsync(pooledS, 0, (size_t)NGRAPHS*128*4, stream);
  k_pool8<<<dim3(NGRAPHS,8),128,0,stream>>>(g3, batch, pooledS);
  k_lin<<<1,1024,0,stream>>>(pooledS, batch, Wlin, blin, out);
}

// Round 16
// 346.575 us; speedup vs baseline: 1.2849x; 1.0523x over previous
//
#include <hip/hip_runtime.h>
#include <math.h>

#define NNODES 50000
#define NEDGES 400000
#define ETOT   (NEDGES + NNODES)
#define NGRAPHS 64
#define NCVT   (NNODES*32)

typedef _Float16 f16;
typedef _Float16 f16x4 __attribute__((ext_vector_type(4)));
typedef _Float16 f16x8 __attribute__((ext_vector_type(8)));
typedef float f32x4 __attribute__((ext_vector_type(4)));

__device__ __forceinline__ float lrelu(float x){ return x >= 0.f ? x : 0.2f*x; }
__device__ __forceinline__ float eluf(float x){ return x > 0.f ? x : expm1f(x); }

// ---------------- CSR build (self-loop at slot 0; deg counts edges only, +1 in scans) ----------------
__global__ void k_hist(const int* __restrict__ ei, int* __restrict__ deg){
  int e = blockIdx.x*blockDim.x + threadIdx.x;
  if (e < NEDGES) atomicAdd(&deg[ei[NEDGES + e]], 1);
}
__global__ void k_scan1(const int* __restrict__ deg, int* __restrict__ part, int n){
  __shared__ int buf[256];
  int i = blockIdx.x*256 + threadIdx.x;
  buf[threadIdx.x] = (i<n)? deg[i]+1 : 0;
  __syncthreads();
  for (int s=128; s>0; s>>=1){ if (threadIdx.x < s) buf[threadIdx.x]+=buf[threadIdx.x+s]; __syncthreads(); }
  if (threadIdx.x==0) part[blockIdx.x]=buf[0];
}
__global__ void k_scan2(const int* __restrict__ part, int* __restrict__ bpre, int* __restrict__ row_off_last, int nb){
  __shared__ int buf[256];
  int t = threadIdx.x;
  int v = (t<nb)? part[t] : 0;
  buf[t]=v; __syncthreads();
  for (int s=1;s<256;s<<=1){ int a = (t>=s)? buf[t-s]:0; __syncthreads(); buf[t]+=a; __syncthreads(); }
  if (t<nb) bpre[t] = buf[t]-v;
  if (t==255) row_off_last[0] = buf[255];
}
__global__ void k_scan3(const int* __restrict__ deg, const int* __restrict__ bpre, int* __restrict__ row_off, int n){
  __shared__ int buf[256];
  int t = threadIdx.x;
  int i = blockIdx.x*256 + t;
  int v = (i<n)? deg[i]+1 : 0;
  buf[t]=v; __syncthreads();
  for (int s=1;s<256;s<<=1){ int a=(t>=s)?buf[t-s]:0; __syncthreads(); buf[t]+=a; __syncthreads(); }
  if (i<n) row_off[i] = bpre[blockIdx.x] + buf[t]-v;
}
__global__ void k_selfpos(const int* __restrict__ row_off, int* __restrict__ csr_src,
                          int* __restrict__ csr_dst, int* __restrict__ cursor){
  int n = blockIdx.x*256 + threadIdx.x;
  if (n < NNODES){
    int p = row_off[n];
    csr_src[p] = n; csr_dst[p] = n;
    cursor[n] = 1;
  }
}
__global__ void k_scatter(const int* __restrict__ ei, const int* __restrict__ row_off,
                          int* __restrict__ cursor, int* __restrict__ csr_src, int* __restrict__ csr_dst){
  int e = blockIdx.x*blockDim.x + threadIdx.x;
  if (e < NEDGES){
    int s = ei[e], d = ei[NEDGES+e];
    int pos = row_off[d] + atomicAdd(&cursor[d],1);
    csr_src[pos] = s; csr_dst[pos] = d;
  }
}

// ---------------- weight prep + x cast (merged) ----------------
__global__ void k_prep(const float* __restrict__ x, f16* __restrict__ xh,
                       const float* __restrict__ W1, const float* __restrict__ W2, const float* __restrict__ W3,
                       const float* __restrict__ as1, const float* __restrict__ ad1,
                       const float* __restrict__ as2, const float* __restrict__ ad2,
                       const float* __restrict__ as3, const float* __restrict__ ad3,
                       f16* __restrict__ BT1, f16* __restrict__ BT2, f16* __restrict__ BT3,
                       f16* __restrict__ PT1x, f16* __restrict__ PT2, f16* __restrict__ PT3){
  int u = blockIdx.x*256 + threadIdx.x;
  if (u < NCVT){
    float4 v = *(const float4*)&x[(size_t)u*4];
    f16x4 o; o[0]=(f16)v.x; o[1]=(f16)v.y; o[2]=(f16)v.z; o[3]=(f16)v.w;
    *(f16x4*)&xh[(size_t)u*4] = o;
    return;
  }
  u -= NCVT;
  if (u < 8192){ int j=u>>7, k=u&127; BT1[j*128+k] = (f16)W1[(size_t)k*64+j]; return; }
  u -= 8192;
  if (u < 16384){ int col=u>>6, k=u&63; BT2[col*64+k] = (f16)W2[(size_t)k*256+col]; return; }
  u -= 16384;
  if (u < 131072){ int j=u>>10, t=u&1023, h=t>>8, c=t&255;
                   BT3[(size_t)j*1024+t] = (f16)W3[(size_t)c*512 + h*128 + j]; return; }
  u -= 131072;
  if (u < 2048){ // PT1x[o][k] = sum_c W1[k][h*16+c] * a1_h[c]
    int o=u>>7, k=u&127; float v=0.f;
    if (o<8){ int h=o&3;
      const float* a=((o<4)?as1:ad1)+h*16; const float* w=W1+(size_t)k*64+h*16;
      for(int c=0;c<16;c++) v=fmaf(w[c],a[c],v); }
    PT1x[u] = (f16)v; return; }
  u -= 2048;
  if (u < 1024){ // PT2[o][k]
    int o=u>>6, k=u&63; float v=0.f;
    if (o<8){ int h=o&3;
      const float* a=((o<4)?as2:ad2)+h*64; const float* w=W2+(size_t)k*256+h*64;
      for(int c=0;c<64;c++) v=fmaf(w[c],a[c],v); }
    PT2[u] = (f16)v; return; }
  u -= 1024;
  if (u < 4096){ // PT3[o][k]
    int o=u>>8, k=u&255; float v=0.f;
    if (o<8){ int h=o&3;
      const float* a=((o<4)?as3:ad3)+h*128; const float* w=W3+(size_t)k*512+h*128;
      for(int c=0;c<128;c++) v=fmaf(w[c],a[c],v); }
    PT3[u] = (f16)v; }
}

// ---------------- scores via MFMA: esd[n][0..3]=es, [4..7]=ed ----------------
template<int KF>
__global__ __launch_bounds__(256) void k_scores_m(const f16* __restrict__ g, const f16* __restrict__ PT,
                                                  float* __restrict__ esd){
  int wv = threadIdx.x>>6, lane = threadIdx.x&63;
  int r = lane&15, kb = lane>>4;
  int row0 = blockIdx.x*64 + wv*16;
  const f16* arow = g + (size_t)(row0+r)*KF + kb*8;
  const f16* brow = PT + (size_t)r*KF + kb*8;
  f32x4 acc = {0,0,0,0};
  #pragma unroll
  for (int k0=0;k0<KF;k0+=32){
    f16x8 af = *(const f16x8*)(arow + k0);
    f16x8 bf = *(const f16x8*)(brow + k0);
    acc = __builtin_amdgcn_mfma_f32_16x16x32_f16(af, bf, acc, 0,0,0);
  }
  if (r < 8){
    #pragma unroll
    for (int i=0;i<4;i++){
      int row = row0 + kb*4 + i;
      if (row < NNODES) esd[(size_t)row*8 + r] = acc[i];
    }
  }
}

// ---------------- edge-parallel softmax numerators: alphaW[p][h] ----------------
__global__ __launch_bounds__(256) void k_expw(const float* __restrict__ esd, const int* __restrict__ csr_src,
                                              const int* __restrict__ csr_dst, float* __restrict__ alphaW){
  int p = blockIdx.x*256 + threadIdx.x;
  if (p >= ETOT) return;
  int s = csr_src[p], d = csr_dst[p];
  float4 a = *(const float4*)&esd[(size_t)s*8];
  float4 b = *(const float4*)&esd[(size_t)d*8+4];
  float4 r;
  r.x = expf(lrelu(a.x+b.x));
  r.y = expf(lrelu(a.y+b.y));
  r.z = expf(lrelu(a.z+b.z));
  r.w = expf(lrelu(a.w+b.w));
  *(float4*)&alphaW[(size_t)p*4] = r;
}

// ---------------- MFMA GEMMs ----------------
// l1: h1[50000,64] = xh @ BT1^T, fused layer-1 scores esd = xh @ PT1x
__global__ __launch_bounds__(256) void k_mfma_l1(const f16* __restrict__ xh, const f16* __restrict__ BT1,
                                                 const f16* __restrict__ PT1x,
                                                 f16* __restrict__ h1h, float* __restrict__ esd){
  int wv = threadIdx.x>>6, lane = threadIdx.x&63;
  int r = lane&15, kb = lane>>4;
  int row0 = blockIdx.x*64 + wv*16;
  const f16* arow = xh + (size_t)(row0 + r)*128 + kb*8;
  f32x4 acc[4] = {{0,0,0,0},{0,0,0,0},{0,0,0,0},{0,0,0,0}};
  f32x4 accs = {0,0,0,0};
  for (int k0=0;k0<128;k0+=32){
    f16x8 af = *(const f16x8*)(arow + k0);
    #pragma unroll
    for (int c=0;c<4;c++){
      f16x8 bf = *(const f16x8*)(BT1 + (size_t)(c*16+r)*128 + k0 + kb*8);
      acc[c] = __builtin_amdgcn_mfma_f32_16x16x32_f16(af, bf, acc[c], 0,0,0);
    }
    f16x8 bs = *(const f16x8*)(PT1x + (size_t)r*128 + k0 + kb*8);
    accs = __builtin_amdgcn_mfma_f32_16x16x32_f16(af, bs, accs, 0,0,0);
  }
  #pragma unroll
  for (int c=0;c<4;c++)
    #pragma unroll
    for (int i=0;i<4;i++){
      int row = row0 + kb*4 + i;
      if (row < NNODES) h1h[(size_t)row*64 + c*16 + r] = (f16)acc[c][i];
    }
  if (r < 8){
    #pragma unroll
    for (int i=0;i<4;i++){
      int row = row0 + kb*4 + i;
      if (row < NNODES) esd[(size_t)row*8 + r] = accs[i];
    }
  }
}

// l2 (per-head): g2[n, h*64+j] = ELU(agg2[n, h*64+:] @ W2_h + b2)
__global__ __launch_bounds__(256) void k_mfma_l2(const f16* __restrict__ agg2h, const f16* __restrict__ BT2,
                                                 const float* __restrict__ b2, f16* __restrict__ g2h){
  int wv = threadIdx.x>>6, lane = threadIdx.x&63;
  int r = lane&15, kb = lane>>4;
  int h = blockIdx.y;
  int row0 = blockIdx.x*64 + wv*16;
  const f16* arow = agg2h + (size_t)(row0 + r)*256 + h*64 + kb*8;
  f32x4 acc[4] = {{0,0,0,0},{0,0,0,0},{0,0,0,0},{0,0,0,0}};
  #pragma unroll
  for (int k0=0;k0<64;k0+=32){
    f16x8 af = *(const f16x8*)(arow + k0);
    #pragma unroll
    for (int c=0;c<4;c++){
      f16x8 bf = *(const f16x8*)(BT2 + (size_t)(h*64+c*16+r)*64 + k0 + kb*8);
      acc[c] = __builtin_amdgcn_mfma_f32_16x16x32_f16(af, bf, acc[c], 0,0,0);
    }
  }
  #pragma unroll
  for (int c=0;c<4;c++){
    int col = h*64 + c*16 + r;
    float bb = b2[col];
    #pragma unroll
    for (int i=0;i<4;i++){
      int row = row0 + kb*4 + i;
      if (row < NNODES) g2h[(size_t)row*256 + col] = (f16)eluf(acc[c][i] + bb);
    }
  }
}

// layer3 final GEMM, LDS-tiled + register prefetch:
// g3[n,128] = ELU(0.25 * aggz[n,1024] @ BT3^T + b3)
__global__ __launch_bounds__(256) void k_mfma_z(const f16* __restrict__ aggz, const f16* __restrict__ BT3,
                                                const float* __restrict__ b3, float* __restrict__ g3){
  __shared__ __align__(16) f16 As[64][72];
  __shared__ __align__(16) f16 Bs[128][72];
  int tid = threadIdx.x;
  int wv = tid>>6, lane = tid&63;
  int r = lane&15, kb = lane>>4;
  int rowbase = blockIdx.x*64;
  int ar = tid>>2, ap = (tid&3)*16;
  int bc = tid>>1, bp = (tid&1)*32;
  const f16* asrc = aggz + (size_t)(rowbase + ar)*1024 + ap;
  const f16* bsrc = BT3 + (size_t)bc*1024 + bp;
  f32x4 acc[8];
  #pragma unroll
  for (int c=0;c<8;c++) acc[c] = (f32x4){0,0,0,0};
  f16x8 ra0, ra1, rb0, rb1, rb2, rb3;
  ra0 = *(const f16x8*)(asrc);      ra1 = *(const f16x8*)(asrc+8);
  rb0 = *(const f16x8*)(bsrc);      rb1 = *(const f16x8*)(bsrc+8);
  rb2 = *(const f16x8*)(bsrc+16);   rb3 = *(const f16x8*)(bsrc+24);
  for (int kc=0; kc<16; ++kc){
    __syncthreads();
    *(f16x8*)&As[ar][ap]    = ra0;  *(f16x8*)&As[ar][ap+8]  = ra1;
    *(f16x8*)&Bs[bc][bp]    = rb0;  *(f16x8*)&Bs[bc][bp+8]  = rb1;
    *(f16x8*)&Bs[bc][bp+16] = rb2;  *(f16x8*)&Bs[bc][bp+24] = rb3;
    __syncthreads();
    if (kc+1 < 16){
      const f16* an = asrc + (kc+1)*64;
      const f16* bn = bsrc + (kc+1)*64;
      ra0 = *(const f16x8*)(an);    ra1 = *(const f16x8*)(an+8);
      rb0 = *(const f16x8*)(bn);    rb1 = *(const f16x8*)(bn+8);
      rb2 = *(const f16x8*)(bn+16); rb3 = *(const f16x8*)(bn+24);
    }
    #pragma unroll
    for (int ks=0;ks<2;ks++){
      f16x8 af = *(const f16x8*)&As[wv*16 + r][ks*32 + kb*8];
      #pragma unroll
      for (int c=0;c<8;c++){
        f16x8 bf = *(const f16x8*)&Bs[c*16 + r][ks*32 + kb*8];
        acc[c] = __builtin_amdgcn_mfma_f32_16x16x32_f16(af, bf, acc[c], 0,0,0);
      }
    }
  }
  #pragma unroll
  for (int c=0;c<8;c++){
    int col = c*16 + r;
    float bb = b3[col];
    #pragma unroll
    for (int i=0;i<4;i++){
      int row = rowbase + wv*16 + kb*4 + i;
      if (row < NNODES) g3[(size_t)row*128 + col] = eluf(0.25f*acc[c][i] + bb);
    }
  }
}

// ---------------- gathers: 1 node/wave, 4-edge software pipeline ----------------
__global__ __launch_bounds__(256) void k_gat1f(const f16* __restrict__ h1h, const float* __restrict__ alphaW,
    const int* __restrict__ row_off, const int* __restrict__ csr_src,
    const float* __restrict__ b1, f16* __restrict__ g1h){
  int n = blockIdx.x*4 + (threadIdx.x>>6);
  if (n >= NNODES) return;
  int t = threadIdx.x & 63;
  int head = t >> 4;
  int pos = row_off[n], end = row_off[n+1];
  float acc = 0.f, den = 0.f;
  for (; pos+3 < end; pos += 4){
    int s0 = csr_src[pos], s1 = csr_src[pos+1], s2 = csr_src[pos+2], s3 = csr_src[pos+3];
    float w0 = alphaW[(size_t)pos*4 + head];
    float w1 = alphaW[(size_t)(pos+1)*4 + head];
    float w2 = alphaW[(size_t)(pos+2)*4 + head];
    float w3 = alphaW[(size_t)(pos+3)*4 + head];
    float v0 = (float)h1h[(size_t)s0*64 + t];
    float v1 = (float)h1h[(size_t)s1*64 + t];
    float v2 = (float)h1h[(size_t)s2*64 + t];
    float v3 = (float)h1h[(size_t)s3*64 + t];
    acc = fmaf(w0, v0, fmaf(w1, v1, fmaf(w2, v2, fmaf(w3, v3, acc))));
    den += (w0 + w1) + (w2 + w3);
  }
  for (; pos < end; ++pos){
    int s0 = csr_src[pos];
    float w0 = alphaW[(size_t)pos*4 + head];
    acc = fmaf(w0, (float)h1h[(size_t)s0*64 + t], acc);
    den += w0;
  }
  g1h[(size_t)n*64 + t] = (f16)eluf(acc/(den + 1e-16f) + b1[t]);
}

__global__ __launch_bounds__(256) void k_agg2f(const f16* __restrict__ g1h, const float* __restrict__ alphaW,
    const int* __restrict__ row_off, const int* __restrict__ csr_src,
    f16* __restrict__ agg2h){
  int n = blockIdx.x*4 + (threadIdx.x>>6);
  if (n >= NNODES) return;
  int t = threadIdx.x & 63;
  int pos = row_off[n], end = row_off[n+1];
  float c0=0.f,c1=0.f,c2=0.f,c3=0.f,d0=0.f,d1=0.f,d2=0.f,d3=0.f;
  for (; pos+3 < end; pos += 4){
    int s0 = csr_src[pos], s1 = csr_src[pos+1], s2 = csr_src[pos+2], s3 = csr_src[pos+3];
    float4 a = *(const float4*)&alphaW[(size_t)pos*4];
    float4 b = *(const float4*)&alphaW[(size_t)(pos+1)*4];
    float4 c = *(const float4*)&alphaW[(size_t)(pos+2)*4];
    float4 d = *(const float4*)&alphaW[(size_t)(pos+3)*4];
    float v0 = (float)g1h[(size_t)s0*64 + t];
    float v1 = (float)g1h[(size_t)s1*64 + t];
    float v2 = (float)g1h[(size_t)s2*64 + t];
    float v3 = (float)g1h[(size_t)s3*64 + t];
    c0=fmaf(a.x,v0,fmaf(b.x,v1,fmaf(c.x,v2,fmaf(d.x,v3,c0))));
    c1=fmaf(a.y,v0,fmaf(b.y,v1,fmaf(c.y,v2,fmaf(d.y,v3,c1))));
    c2=fmaf(a.z,v0,fmaf(b.z,v1,fmaf(c.z,v2,fmaf(d.z,v3,c2))));
    c3=fmaf(a.w,v0,fmaf(b.w,v1,fmaf(c.w,v2,fmaf(d.w,v3,c3))));
    d0+=(a.x+b.x)+(c.x+d.x); d1+=(a.y+b.y)+(c.y+d.y);
    d2+=(a.z+b.z)+(c.z+d.z); d3+=(a.w+b.w)+(c.w+d.w);
  }
  for (; pos < end; ++pos){
    int s0 = csr_src[pos];
    float4 a = *(const float4*)&alphaW[(size_t)pos*4];
    float v0 = (float)g1h[(size_t)s0*64 + t];
    c0=fmaf(a.x,v0,c0); c1=fmaf(a.y,v0,c1); c2=fmaf(a.z,v0,c2); c3=fmaf(a.w,v0,c3);
    d0+=a.x; d1+=a.y; d2+=a.z; d3+=a.w;
  }
  size_t base = (size_t)n*256;
  agg2h[base       + t] = (f16)(c0/(d0+1e-16f));
  agg2h[base +  64 + t] = (f16)(c1/(d1+1e-16f));
  agg2h[base + 128 + t] = (f16)(c2/(d2+1e-16f));
  agg2h[base + 192 + t] = (f16)(c3/(d3+1e-16f));
}

// layer3 pre-GEMM aggregation: aggz[n][h*256+c] = (sum_e alpha_eh g2[src][c]) / den_h
__global__ __launch_bounds__(256) void k_agg3n(const f16* __restrict__ g2h, const float* __restrict__ alphaW,
    const int* __restrict__ row_off, const int* __restrict__ csr_src,
    f16* __restrict__ aggz){
  int n = blockIdx.x*4 + (threadIdx.x>>6);
  if (n >= NNODES) return;
  int lane = threadIdx.x & 63;
  int pos = row_off[n], end = row_off[n+1];
  float acc[4][4] = {};
  float d0=0.f,d1=0.f,d2=0.f,d3=0.f;
  for (; pos+3 < end; pos += 4){
    int s0 = csr_src[pos], s1 = csr_src[pos+1], s2 = csr_src[pos+2], s3 = csr_src[pos+3];
    float4 a = *(const float4*)&alphaW[(size_t)pos*4];
    float4 b = *(const float4*)&alphaW[(size_t)(pos+1)*4];
    float4 c = *(const float4*)&alphaW[(size_t)(pos+2)*4];
    float4 d = *(const float4*)&alphaW[(size_t)(pos+3)*4];
    f16x4 u0 = *(const f16x4*)&g2h[(size_t)s0*256 + lane*4];
    f16x4 u1 = *(const f16x4*)&g2h[(size_t)s1*256 + lane*4];
    f16x4 u2 = *(const f16x4*)&g2h[(size_t)s2*256 + lane*4];
    f16x4 u3 = *(const f16x4*)&g2h[(size_t)s3*256 + lane*4];
    float wa[4] = {a.x,a.y,a.z,a.w};
    float wb[4] = {b.x,b.y,b.z,b.w};
    float wc[4] = {c.x,c.y,c.z,c.w};
    float wd[4] = {d.x,d.y,d.z,d.w};
    #pragma unroll
    for (int h=0;h<4;h++)
      #pragma unroll
      for (int j=0;j<4;j++)
        acc[h][j] = fmaf(wa[h],(float)u0[j], fmaf(wb[h],(float)u1[j],
                    fmaf(wc[h],(float)u2[j], fmaf(wd[h],(float)u3[j], acc[h][j]))));
    d0 += (a.x+b.x)+(c.x+d.x); d1 += (a.y+b.y)+(c.y+d.y);
    d2 += (a.z+b.z)+(c.z+d.z); d3 += (a.w+b.w)+(c.w+d.w);
  }
  for (; pos < end; ++pos){
    int s0 = csr_src[pos];
    float4 a = *(const float4*)&alphaW[(size_t)pos*4];
    f16x4 u0 = *(const f16x4*)&g2h[(size_t)s0*256 + lane*4];
    float wa[4] = {a.x,a.y,a.z,a.w};
    #pragma unroll
    for (int h=0;h<4;h++)
      #pragma unroll
      for (int j=0;j<4;j++)
        acc[h][j] = fmaf(wa[h], (float)u0[j], acc[h][j]);
    d0 += a.x; d1 += a.y; d2 += a.z; d3 += a.w;
  }
  float dn[4] = {d0+1e-16f, d1+1e-16f, d2+1e-16f, d3+1e-16f};
  #pragma unroll
  for (int h=0;h<4;h++){
    f16x4 o;
    #pragma unroll
    for (int j=0;j<4;j++) o[j] = (f16)(acc[h][j]/dn[h]);
    *(f16x4*)&aggz[(size_t)n*1024 + h*256 + lane*4] = o;
  }
}

// ---------------- pooling + linear head ----------------
__device__ __forceinline__ int lowerb(const int* a, int n, int v){
  int lo=0, hi=n;
  while (lo<hi){ int mid=(lo+hi)>>1; if (a[mid]<v) lo=mid+1; else hi=mid; }
  return lo;
}
__global__ void k_pool8(const float* __restrict__ g3, const int* __restrict__ batch, float* __restrict__ pooledS){
  int g = blockIdx.x, ch = blockIdx.y, c = threadIdx.x;
  int lo = lowerb(batch, NNODES, g);
  int hi = lowerb(batch, NNODES, g+1);
  int len = hi - lo;
  int b0 = lo + (len*ch)/8, b1 = lo + (len*(ch+1))/8;
  float s = 0.f;
  for (int nn=b0; nn<b1; ++nn) s += g3[(size_t)nn*128 + c];
  if (b1 > b0) atomicAdd(&pooledS[g*128+c], s);
}
__global__ void k_lin(const float* __restrict__ pooledS, const int* __restrict__ batch,
                      const float* __restrict__ Wlin, const float* __restrict__ blin, float* __restrict__ out){
  int t = threadIdx.x;
  if (t < 640){
    int g = t/10, j = t%10;
    int lo = lowerb(batch, NNODES, g);
    int hi = lowerb(batch, NNODES, g+1);
    float inv = 1.f / fmaxf((float)(hi-lo), 1.f);
    float s = blin[j];
    for (int c=0;c<128;c++) s = fmaf(pooledS[g*128+c]*inv, Wlin[c*10+j], s);
    out[t] = s;
  }
}

extern "C" void kernel_launch(void* const* d_in, const int* in_sizes, int n_in,
                              void* d_out, int out_size, void* d_ws, size_t ws_size,
                              hipStream_t stream){
  (void)in_sizes; (void)n_in; (void)out_size; (void)ws_size;
  const float* x    = (const float*)d_in[0];
  const int*   ei   = (const int*)d_in[1];
  const int*   batch= (const int*)d_in[2];
  const float* W1   = (const float*)d_in[3];
  const float* as1  = (const float*)d_in[4];
  const float* ad1  = (const float*)d_in[5];
  const float* b1   = (const float*)d_in[6];
  const float* W2   = (const float*)d_in[7];
  const float* as2  = (const float*)d_in[8];
  const float* ad2  = (const float*)d_in[9];
  const float* b2   = (const float*)d_in[10];
  const float* W3   = (const float*)d_in[11];
  const float* as3  = (const float*)d_in[12];
  const float* ad3  = (const float*)d_in[13];
  const float* b3   = (const float*)d_in[14];
  const float* Wlin = (const float*)d_in[15];
  const float* blin = (const float*)d_in[16];
  float* out = (float*)d_out;

  char* ws = (char*)d_ws;
  size_t off = 0;
  auto alloc = [&](size_t bytes)->char*{ char* p = ws + off; off += (bytes + 255) & ~(size_t)255; return p; };
  int* csr_src = (int*)alloc((size_t)ETOT*4);
  int* csr_dst = (int*)alloc((size_t)ETOT*4);
  int* row_off = (int*)alloc((size_t)(NNODES+1)*4);
  int* deg     = (int*)alloc((size_t)NNODES*4);
  int* cursor  = (int*)alloc((size_t)NNODES*4);
  int* part    = (int*)alloc(256*4);
  int* bpre    = (int*)alloc(256*4);
  float* esd   = (float*)alloc((size_t)NNODES*8*4);
  float* alphaW= (float*)alloc((size_t)ETOT*4*4);
  f16* BT1     = (f16*)alloc(8192*2);
  f16* BT2     = (f16*)alloc(16384*2);
  f16* BT3     = (f16*)alloc(131072*2);
  f16* PT1x    = (f16*)alloc(2048*2);
  f16* PT2     = (f16*)alloc(1024*2);
  f16* PT3     = (f16*)alloc(4096*2);
  float* pooledS = (float*)alloc((size_t)NGRAPHS*128*4);
  // g2h FIRST so the following five regions are contiguous and alias-able as aggz.
  f16* g2h     = (f16*)alloc((size_t)NNODES*256*2);   // 25.6 MB (live through layer 3)
  f16* xh      = (f16*)alloc((size_t)NNODES*128*2);   // 12.8 MB (aggz part 1)
  f16* h1h     = (f16*)alloc((size_t)NNODES*64*2);    //  6.4 MB (aggz part 2)
  f16* g1h     = (f16*)alloc((size_t)NNODES*64*2);    //  6.4 MB (aggz part 3)
  f16* agg2h   = (f16*)alloc((size_t)NNODES*256*2);   // 25.6 MB (aggz part 4)
  alloc((size_t)NNODES*512*2);                        // 51.2 MB zslab (aggz part 5)
  float* g3    = (float*)alloc((size_t)NNODES*128*4); // 25.6 MB (absorbs OOB-read tails)
  f16* aggz    = xh;  // [NNODES][1024] f16 spanning xh..zslab (all dead by agg3n)

  int nbE = (NEDGES+255)/256;
  int nbS = (NNODES+255)/256;
  int nbP = (ETOT+255)/256;
  int nb4 = (NNODES+3)/4;

  // CSR with self-loop at slot 0 of each row (deg holds edge count; +1 in scans)
  hipMemsetAsync(deg, 0, (size_t)NNODES*4, stream);
  k_hist<<<nbE,256,0,stream>>>(ei, deg);
  k_scan1<<<nbS,256,0,stream>>>(deg, part, NNODES);
  k_scan2<<<1,256,0,stream>>>(part, bpre, row_off+NNODES, nbS);
  k_scan3<<<nbS,256,0,stream>>>(deg, bpre, row_off, NNODES);
  k_selfpos<<<nbS,256,0,stream>>>(row_off, csr_src, csr_dst, cursor);
  k_scatter<<<nbE,256,0,stream>>>(ei, row_off, cursor, csr_src, csr_dst);

  // weight prep + x cast (merged)
  k_prep<<<6886,256,0,stream>>>(x, xh, W1,W2,W3,as1,ad1,as2,ad2,as3,ad3,BT1,BT2,BT3,PT1x,PT2,PT3);

  // layer 1 (scores fused into the GEMM)
  k_mfma_l1<<<782,256,0,stream>>>(xh, BT1, PT1x, h1h, esd);
  k_expw<<<nbP,256,0,stream>>>(esd, csr_src, csr_dst, alphaW);
  k_gat1f<<<nb4,256,0,stream>>>(h1h, alphaW, row_off, csr_src, b1, g1h);

  // layer 2
  k_scores_m<64><<<782,256,0,stream>>>(g1h, PT2, esd);
  k_expw<<<nbP,256,0,stream>>>(esd, csr_src, csr_dst, alphaW);
  k_agg2f<<<nb4,256,0,stream>>>(g1h, alphaW, row_off, csr_src, agg2h);
  k_mfma_l2<<<dim3(782,4),256,0,stream>>>(agg2h, BT2, b2, g2h);

  // layer 3: scores -> expw -> narrow gather (g2h, 512 B/edge) -> LDS-tiled K=1024 GEMM
  k_scores_m<256><<<782,256,0,stream>>>(g2h, PT3, esd);
  k_expw<<<nbP,256,0,stream>>>(esd, csr_src, csr_dst, alphaW);
  k_agg3n<<<nb4,256,0,stream>>>(g2h, alphaW, row_off, csr_src, aggz);
  k_mfma_z<<<782,256,0,stream>>>(aggz, BT3, b3, g3);

  // pool + linear
  hipMemsetAsync(pooledS, 0, (size_t)NGRAPHS*128*4, stream);
  k_pool8<<<dim3(NGRAPHS,8),128,0,stream>>>(g3, batch, pooledS);
  k_lin<<<1,1024,0,stream>>>(pooledS, batch, Wlin, blin, out);
}